// Round 1
// baseline (1293.647 us; speedup 1.0000x reference)
//
#include <hip/hip_runtime.h>

// Problem constants (from reference)
#define N_SRC1 200000
#define N_TGT1 50000
#define N_TGT2 10000
#define E1_N   1000000
#define E2_N   300000
#define F_IN   256
#define F_HID  192
#define F_OUT  128

// ---------------------------------------------------------------------------
// Edge scatter: one wave (64 lanes) per edge. seg[tgt] += X[src], cnt[tgt]++.
// ---------------------------------------------------------------------------
__global__ __launch_bounds__(256) void scatter_edges(
    const int* __restrict__ src, const int* __restrict__ tgt,
    const float* __restrict__ X, int F, int E,
    float* __restrict__ seg, unsigned int* __restrict__ cnt)
{
    long long gid = (long long)blockIdx.x * blockDim.x + threadIdx.x;
    int e    = (int)(gid >> 6);
    int lane = (int)(gid & 63);
    if (e >= E) return;
    int s = src[e], t = tgt[e];
    if (lane == 0) atomicAdd(cnt + t, 1u);
    const float* xr = X + (size_t)s * F;
    float*       sr = seg + (size_t)t * F;
    for (int f = lane; f < F; f += 64) atomicAdd(sr + f, xr[f]);
}

__global__ __launch_bounds__(256) void make_inv(
    const unsigned int* __restrict__ cnt, float* __restrict__ inv, int n)
{
    int i = blockIdx.x * blockDim.x + threadIdx.x;
    if (i < n) {
        unsigned int c = cnt[i];
        inv[i] = 1.0f / (float)(c > 1u ? c : 1u);
    }
}

// ---------------------------------------------------------------------------
// Fused two-input GEMM:
//   C[m,n] = act( sum_{k<K1} A1[m,k]*scale1[m]*Wa[n,k]
//               + sum_{k<K2} A2[m,k]*Wb[n,k] + bias[n] )
// A1 is the segment-sum (scale1 = 1/count applies the mean on load).
// Optionally writes pre-activation to C2 (for embedding output).
// Requires K1 % 16 == 0, (K1+K2) % 16 == 0.
// ---------------------------------------------------------------------------
#define BM 64
#define BN 64
#define BK 16

__global__ __launch_bounds__(256) void gemm_fused(
    const float* __restrict__ A1, const float* __restrict__ scale1, int K1,
    const float* __restrict__ A2, int K2,
    const float* __restrict__ Wa, const float* __restrict__ Wb,
    const float* __restrict__ bias,
    float* __restrict__ C, float* __restrict__ C2,
    int M, int N, int relu)
{
    __shared__ float As[BK][BM + 4];
    __shared__ float Ws[BK][BN + 4];
    const int tid = threadIdx.x;
    const int tx = tid & 15, ty = tid >> 4;
    const int lr = tid >> 2;        // 0..63  (row within tile for loading)
    const int lc = (tid & 3) * 4;   // 0,4,8,12 (k within BK chunk)
    const int bm = blockIdx.x * BM;
    const int bn = blockIdx.y * BN;
    const int K = K1 + K2;
    float acc[4][4] = {};

    for (int k0 = 0; k0 < K; k0 += BK) {
        // ---- load A tile (64 x 16) ----
        {
            int m = bm + lr;
            int k = k0 + lc;
            float4 v = make_float4(0.f, 0.f, 0.f, 0.f);
            if (m < M) {
                if (k < K1) {
                    v = *(const float4*)(A1 + (size_t)m * K1 + k);
                    if (scale1) { float s = scale1[m]; v.x *= s; v.y *= s; v.z *= s; v.w *= s; }
                } else {
                    v = *(const float4*)(A2 + (size_t)m * K2 + (k - K1));
                }
            }
            As[lc + 0][lr] = v.x; As[lc + 1][lr] = v.y;
            As[lc + 2][lr] = v.z; As[lc + 3][lr] = v.w;
        }
        // ---- load W tile (64 x 16) ----
        {
            int n = bn + lr;
            int k = k0 + lc;
            float4 v = make_float4(0.f, 0.f, 0.f, 0.f);
            if (n < N) {
                if (k < K1) v = *(const float4*)(Wa + (size_t)n * K1 + k);
                else        v = *(const float4*)(Wb + (size_t)n * K2 + (k - K1));
            }
            Ws[lc + 0][lr] = v.x; Ws[lc + 1][lr] = v.y;
            Ws[lc + 2][lr] = v.z; Ws[lc + 3][lr] = v.w;
        }
        __syncthreads();
#pragma unroll
        for (int kk = 0; kk < BK; ++kk) {
            float av[4], wv[4];
#pragma unroll
            for (int i = 0; i < 4; ++i) av[i] = As[kk][ty * 4 + i];
#pragma unroll
            for (int j = 0; j < 4; ++j) wv[j] = Ws[kk][tx * 4 + j];
#pragma unroll
            for (int i = 0; i < 4; ++i)
#pragma unroll
                for (int j = 0; j < 4; ++j)
                    acc[i][j] = fmaf(av[i], wv[j], acc[i][j]);
        }
        __syncthreads();
    }

#pragma unroll
    for (int i = 0; i < 4; ++i) {
        int m = bm + ty * 4 + i;
        if (m >= M) continue;
#pragma unroll
        for (int j = 0; j < 4; ++j) {
            int n = bn + tx * 4 + j;
            if (n >= N) continue;
            float v = acc[i][j] + (bias ? bias[n] : 0.f);
            if (C2) C2[(size_t)m * N + n] = v;
            C[(size_t)m * N + n] = relu ? fmaxf(v, 0.f) : v;
        }
    }
}

// ---------------------------------------------------------------------------
// log_softmax over rows of 128: one wave per row, 2 elements per lane.
// ---------------------------------------------------------------------------
__global__ __launch_bounds__(256) void logsoftmax128(
    const float* __restrict__ logits, float* __restrict__ out, int M)
{
    long long gid = (long long)blockIdx.x * blockDim.x + threadIdx.x;
    int row  = (int)(gid >> 6);
    int lane = (int)(gid & 63);
    if (row >= M) return;
    const float* r = logits + (size_t)row * 128;
    float a = r[lane], b = r[lane + 64];
    float mx = fmaxf(a, b);
#pragma unroll
    for (int o = 32; o > 0; o >>= 1) mx = fmaxf(mx, __shfl_xor(mx, o));
    float s = expf(a - mx) + expf(b - mx);
#pragma unroll
    for (int o = 32; o > 0; o >>= 1) s += __shfl_xor(s, o);
    float ls = logf(s) + mx;
    out[(size_t)row * 128 + lane]      = a - ls;
    out[(size_t)row * 128 + lane + 64] = b - ls;
}

// ---------------------------------------------------------------------------
extern "C" void kernel_launch(void* const* d_in, const int* in_sizes, int n_in,
                              void* d_out, int out_size, void* d_ws, size_t ws_size,
                              hipStream_t stream)
{
    const float* x   = (const float*)d_in[0];
    const int*   ei1 = (const int*)d_in[1];
    const int*   ei2 = (const int*)d_in[2];
    const float* Wl1 = (const float*)d_in[3];
    const float* bl1 = (const float*)d_in[4];
    const float* Wr1 = (const float*)d_in[5];
    const float* Wl2 = (const float*)d_in[6];
    const float* bl2 = (const float*)d_in[7];
    const float* Wr2 = (const float*)d_in[8];
    const float* W1  = (const float*)d_in[9];
    const float* b1  = (const float*)d_in[10];
    const float* W2  = (const float*)d_in[11];
    const float* b2  = (const float*)d_in[12];

    char* ws = (char*)d_ws;
    float*        seg1   = (float*)(ws + 0);           //  51,200,000 B [50000*256]
    unsigned int* cnt1   = (unsigned int*)(ws + 51200000);  // 200,000 B
    float*        inv1   = (float*)(ws + 51400000);    //     200,000 B
    float*        h1     = (float*)(ws + 51600000);    //  38,400,000 B [50000*192]
    float*        seg2   = (float*)(ws + 90000000);    //   7,680,000 B [10000*192]
    unsigned int* cnt2   = (unsigned int*)(ws + 97680000);  //  40,000 B
    float*        inv2   = (float*)(ws + 97720000);    //      40,000 B
    float*        h2     = (float*)(ws + 97760000);    //   7,680,000 B
    float*        h3     = (float*)(ws + 105440000);   //   7,680,000 B
    float*        logits = (float*)(ws + 113120000);   //   5,120,000 B

    float* out_ls  = (float*)d_out;                    // [10000,128]
    float* out_emb = (float*)d_out + (size_t)N_TGT2 * F_OUT;  // [10000,192]

    // zero accumulators (seg+cnt adjacent, one memset each layer)
    hipMemsetAsync(seg1, 0, 51200000 + 200000, stream);
    hipMemsetAsync(seg2, 0, 7680000 + 40000, stream);

    // ---- layer 1: aggregate ----
    scatter_edges<<<(E1_N * 64 + 255) / 256, 256, 0, stream>>>(
        ei1, ei1 + E1_N, x, F_IN, E1_N, seg1, cnt1);
    make_inv<<<(N_TGT1 + 255) / 256, 256, 0, stream>>>(cnt1, inv1, N_TGT1);

    // h1 = relu(mean_agg @ Wl1^T + x[:50000] @ Wr1^T + bl1)
    gemm_fused<<<dim3((N_TGT1 + BM - 1) / BM, F_HID / BN), 256, 0, stream>>>(
        seg1, inv1, F_IN, x, F_IN, Wl1, Wr1, bl1, h1, nullptr, N_TGT1, F_HID, 1);

    // ---- layer 2: aggregate ----
    scatter_edges<<<(E2_N * 64 + 255) / 256, 256, 0, stream>>>(
        ei2, ei2 + E2_N, h1, F_HID, E2_N, seg2, cnt2);
    make_inv<<<(N_TGT2 + 255) / 256, 256, 0, stream>>>(cnt2, inv2, N_TGT2);

    // h2 = relu(mean_agg2 @ Wl2^T + h1[:10000] @ Wr2^T + bl2)
    gemm_fused<<<dim3((N_TGT2 + BM - 1) / BM, F_HID / BN), 256, 0, stream>>>(
        seg2, inv2, F_HID, h1, F_HID, Wl2, Wr2, bl2, h2, nullptr, N_TGT2, F_HID, 1);

    // embedding = h2 @ W1^T + b1 (pre-act -> out_emb), h3 = relu(embedding)
    gemm_fused<<<dim3((N_TGT2 + BM - 1) / BM, F_HID / BN), 256, 0, stream>>>(
        h2, nullptr, F_HID, nullptr, 0, W1, nullptr, b1, h3, out_emb, N_TGT2, F_HID, 1);

    // logits = h3 @ W2^T + b2
    gemm_fused<<<dim3((N_TGT2 + BM - 1) / BM, F_OUT / BN), 256, 0, stream>>>(
        h3, nullptr, F_HID, nullptr, 0, W2, nullptr, b2, logits, nullptr, N_TGT2, F_OUT, 0);

    // log_softmax rows of 128
    logsoftmax128<<<(N_TGT2 * 64 + 255) / 256, 256, 0, stream>>>(logits, out_ls, N_TGT2);
}

// Round 2
// 630.734 us; speedup vs baseline: 2.0510x; 2.0510x over previous
//
#include <hip/hip_runtime.h>

// Problem constants (from reference)
#define N_SRC1 200000
#define N_TGT1 50000
#define N_TGT2 10000
#define E1_N   1000000
#define E2_N   300000
#define F_IN   256
#define F_HID  192
#define F_OUT  128

// ---------------------------------------------------------------------------
// CSR build: histogram -> 3-phase exclusive scan -> edge fill
// ---------------------------------------------------------------------------
__global__ __launch_bounds__(256) void hist_kernel(
    const int* __restrict__ tgt, int* __restrict__ cnt, int E)
{
    int i = blockIdx.x * blockDim.x + threadIdx.x;
    if (i < E) atomicAdd(cnt + tgt[i], 1);
}

__global__ __launch_bounds__(256) void scan_blocks(
    const int* __restrict__ cnt, int n, int* __restrict__ off,
    int* __restrict__ partials)
{
    __shared__ int s[256];
    int tid = threadIdx.x;
    int i = blockIdx.x * 256 + tid;
    int v = (i < n) ? cnt[i] : 0;
    s[tid] = v;
    __syncthreads();
#pragma unroll
    for (int o = 1; o < 256; o <<= 1) {
        int t = (tid >= o) ? s[tid - o] : 0;
        __syncthreads();
        s[tid] += t;
        __syncthreads();
    }
    if (i < n) off[i] = s[tid] - v;   // exclusive within block
    if (tid == 255) partials[blockIdx.x] = s[255];
}

__global__ void scan_partials_serial(int* partials, int np, int* total_out)
{
    int run = 0;
    for (int i = 0; i < np; ++i) { int t = partials[i]; partials[i] = run; run += t; }
    *total_out = run;
}

__global__ __launch_bounds__(256) void add_off(
    int* __restrict__ off, const int* __restrict__ partials,
    int* __restrict__ cur, int n)
{
    int i = blockIdx.x * blockDim.x + threadIdx.x;
    if (i < n) {
        int v = off[i] + partials[i >> 8];
        off[i] = v;
        cur[i] = v;
    }
}

__global__ __launch_bounds__(256) void fill_edges(
    const int* __restrict__ src, const int* __restrict__ tgt,
    int* __restrict__ cur, int* __restrict__ esrc, int E)
{
    int i = blockIdx.x * blockDim.x + threadIdx.x;
    if (i < E) {
        int pos = atomicAdd(cur + tgt[i], 1);
        esrc[pos] = src[i];
    }
}

// ---------------------------------------------------------------------------
// CSR aggregation: one wave per target node. acc in registers, write once.
// Mean (1/count) folded into the store.
// ---------------------------------------------------------------------------
template <int F>
__global__ __launch_bounds__(256) void aggregate_csr(
    const int* __restrict__ esrc, const int* __restrict__ off,
    const float* __restrict__ X, float* __restrict__ seg, int n)
{
    int wid  = blockIdx.x * (blockDim.x >> 6) + (threadIdx.x >> 6);
    int lane = threadIdx.x & 63;
    if (wid >= n) return;
    int s0 = off[wid], s1 = off[wid + 1];
    float acc[F / 64] = {};
    for (int e = s0; e < s1; ++e) {
        const float* xr = X + (size_t)esrc[e] * F;
#pragma unroll
        for (int j = 0; j < F / 64; ++j) acc[j] += xr[lane + 64 * j];
    }
    float inv = (s1 > s0) ? 1.0f / (float)(s1 - s0) : 0.0f;
    float* sr = seg + (size_t)wid * F;
#pragma unroll
    for (int j = 0; j < F / 64; ++j) sr[lane + 64 * j] = acc[j] * inv;
}

// ---------------------------------------------------------------------------
// Fused two-input GEMM:
//   C[m,n] = act( sum_{k<K1} A1[m,k]*Wa[n,k] + sum_{k<K2} A2[m,k]*Wb[n,k] + bias[n] )
// ---------------------------------------------------------------------------
#define BM 64
#define BN 64
#define BK 16

__global__ __launch_bounds__(256) void gemm_fused(
    const float* __restrict__ A1, int K1,
    const float* __restrict__ A2, int K2,
    const float* __restrict__ Wa, const float* __restrict__ Wb,
    const float* __restrict__ bias,
    float* __restrict__ C, float* __restrict__ C2,
    int M, int N, int relu)
{
    __shared__ float As[BK][BM + 4];
    __shared__ float Ws[BK][BN + 4];
    const int tid = threadIdx.x;
    const int tx = tid & 15, ty = tid >> 4;
    const int lr = tid >> 2;        // 0..63  (row within tile for loading)
    const int lc = (tid & 3) * 4;   // 0,4,8,12 (k within BK chunk)
    const int bm = blockIdx.x * BM;
    const int bn = blockIdx.y * BN;
    const int K = K1 + K2;
    float acc[4][4] = {};

    for (int k0 = 0; k0 < K; k0 += BK) {
        {
            int m = bm + lr;
            int k = k0 + lc;
            float4 v = make_float4(0.f, 0.f, 0.f, 0.f);
            if (m < M) {
                if (k < K1) v = *(const float4*)(A1 + (size_t)m * K1 + k);
                else        v = *(const float4*)(A2 + (size_t)m * K2 + (k - K1));
            }
            As[lc + 0][lr] = v.x; As[lc + 1][lr] = v.y;
            As[lc + 2][lr] = v.z; As[lc + 3][lr] = v.w;
        }
        {
            int n = bn + lr;
            int k = k0 + lc;
            float4 v = make_float4(0.f, 0.f, 0.f, 0.f);
            if (n < N) {
                if (k < K1) v = *(const float4*)(Wa + (size_t)n * K1 + k);
                else        v = *(const float4*)(Wb + (size_t)n * K2 + (k - K1));
            }
            Ws[lc + 0][lr] = v.x; Ws[lc + 1][lr] = v.y;
            Ws[lc + 2][lr] = v.z; Ws[lc + 3][lr] = v.w;
        }
        __syncthreads();
#pragma unroll
        for (int kk = 0; kk < BK; ++kk) {
            float av[4], wv[4];
#pragma unroll
            for (int i = 0; i < 4; ++i) av[i] = As[kk][ty * 4 + i];
#pragma unroll
            for (int j = 0; j < 4; ++j) wv[j] = Ws[kk][tx * 4 + j];
#pragma unroll
            for (int i = 0; i < 4; ++i)
#pragma unroll
                for (int j = 0; j < 4; ++j)
                    acc[i][j] = fmaf(av[i], wv[j], acc[i][j]);
        }
        __syncthreads();
    }

#pragma unroll
    for (int i = 0; i < 4; ++i) {
        int m = bm + ty * 4 + i;
        if (m >= M) continue;
#pragma unroll
        for (int j = 0; j < 4; ++j) {
            int n = bn + tx * 4 + j;
            if (n >= N) continue;
            float v = acc[i][j] + (bias ? bias[n] : 0.f);
            if (C2) C2[(size_t)m * N + n] = v;
            C[(size_t)m * N + n] = relu ? fmaxf(v, 0.f) : v;
        }
    }
}

// ---------------------------------------------------------------------------
// log_softmax over rows of 128: one wave per row, 2 elements per lane.
// ---------------------------------------------------------------------------
__global__ __launch_bounds__(256) void logsoftmax128(
    const float* __restrict__ logits, float* __restrict__ out, int M)
{
    long long gid = (long long)blockIdx.x * blockDim.x + threadIdx.x;
    int row  = (int)(gid >> 6);
    int lane = (int)(gid & 63);
    if (row >= M) return;
    const float* r = logits + (size_t)row * 128;
    float a = r[lane], b = r[lane + 64];
    float mx = fmaxf(a, b);
#pragma unroll
    for (int o = 32; o > 0; o >>= 1) mx = fmaxf(mx, __shfl_xor(mx, o));
    float s = expf(a - mx) + expf(b - mx);
#pragma unroll
    for (int o = 32; o > 0; o >>= 1) s += __shfl_xor(s, o);
    float ls = logf(s) + mx;
    out[(size_t)row * 128 + lane]      = a - ls;
    out[(size_t)row * 128 + lane + 64] = b - ls;
}

// ---------------------------------------------------------------------------
extern "C" void kernel_launch(void* const* d_in, const int* in_sizes, int n_in,
                              void* d_out, int out_size, void* d_ws, size_t ws_size,
                              hipStream_t stream)
{
    const float* x   = (const float*)d_in[0];
    const int*   ei1 = (const int*)d_in[1];
    const int*   ei2 = (const int*)d_in[2];
    const float* Wl1 = (const float*)d_in[3];
    const float* bl1 = (const float*)d_in[4];
    const float* Wr1 = (const float*)d_in[5];
    const float* Wl2 = (const float*)d_in[6];
    const float* bl2 = (const float*)d_in[7];
    const float* Wr2 = (const float*)d_in[8];
    const float* W1  = (const float*)d_in[9];
    const float* b1  = (const float*)d_in[10];
    const float* W2  = (const float*)d_in[11];
    const float* b2  = (const float*)d_in[12];

    char* ws = (char*)d_ws;
    // big buffers
    float* seg1   = (float*)(ws + 0);            // 51,200,000 B [50000*256]
    float* h1     = (float*)(ws + 51200000);     // 38,400,000 B [50000*192]
    float* seg2   = (float*)(ws + 89600000);     //  7,680,000 B [10000*192]
    int*   esrc1  = (int*)  (ws + 97280000);     //  4,000,000 B
    int*   esrc2  = (int*)  (ws + 101280000);    //  1,200,000 B
    int*   cnt1   = (int*)  (ws + 102480000);    //    200,000 B
    int*   off1   = (int*)  (ws + 102680000);    //    200,016 B (n+1)
    int*   cur1   = (int*)  (ws + 102880016);    //    200,000 B
    int*   cnt2   = (int*)  (ws + 103080016);    //     40,000 B
    int*   off2   = (int*)  (ws + 103120016);    //     40,016 B (n+1)
    int*   cur2   = (int*)  (ws + 103160032);    //     40,000 B
    int*   part   = (int*)  (ws + 103200032);    //      1,024 B
    // reuse seg1 space after GEMM1 consumes it
    float* h2     = (float*)(ws + 0);            //  7,680,000 B
    float* h3     = (float*)(ws + 7680000);      //  7,680,000 B
    float* logits = (float*)(ws + 15360000);     //  5,120,000 B

    float* out_ls  = (float*)d_out;                           // [10000,128]
    float* out_emb = (float*)d_out + (size_t)N_TGT2 * F_OUT;  // [10000,192]

    const int NP1 = (N_TGT1 + 255) / 256;  // 196
    const int NP2 = (N_TGT2 + 255) / 256;  // 40

    // ---- layer 1: CSR build + aggregate ----
    hipMemsetAsync(cnt1, 0, 200000, stream);
    hist_kernel<<<(E1_N + 255) / 256, 256, 0, stream>>>(ei1 + E1_N, cnt1, E1_N);
    scan_blocks<<<NP1, 256, 0, stream>>>(cnt1, N_TGT1, off1, part);
    scan_partials_serial<<<1, 1, 0, stream>>>(part, NP1, off1 + N_TGT1);
    add_off<<<NP1, 256, 0, stream>>>(off1, part, cur1, N_TGT1);
    fill_edges<<<(E1_N + 255) / 256, 256, 0, stream>>>(ei1, ei1 + E1_N, cur1, esrc1, E1_N);
    aggregate_csr<F_IN><<<(N_TGT1 + 3) / 4, 256, 0, stream>>>(esrc1, off1, x, seg1, N_TGT1);

    // h1 = relu([mean_agg | x_tgt] @ [Wl1|Wr1]^T + bl1)
    gemm_fused<<<dim3((N_TGT1 + BM - 1) / BM, F_HID / BN), 256, 0, stream>>>(
        seg1, F_IN, x, F_IN, Wl1, Wr1, bl1, h1, nullptr, N_TGT1, F_HID, 1);

    // ---- layer 2: CSR build + aggregate ----
    hipMemsetAsync(cnt2, 0, 40000, stream);
    hist_kernel<<<(E2_N + 255) / 256, 256, 0, stream>>>(ei2 + E2_N, cnt2, E2_N);
    scan_blocks<<<NP2, 256, 0, stream>>>(cnt2, N_TGT2, off2, part);
    scan_partials_serial<<<1, 1, 0, stream>>>(part, NP2, off2 + N_TGT2);
    add_off<<<NP2, 256, 0, stream>>>(off2, part, cur2, N_TGT2);
    fill_edges<<<(E2_N + 255) / 256, 256, 0, stream>>>(ei2, ei2 + E2_N, cur2, esrc2, E2_N);
    aggregate_csr<F_HID><<<(N_TGT2 + 3) / 4, 256, 0, stream>>>(esrc2, off2, h1, seg2, N_TGT2);

    // h2 = relu([mean_agg2 | h1_tgt] @ [Wl2|Wr2]^T + bl2)
    gemm_fused<<<dim3((N_TGT2 + BM - 1) / BM, F_HID / BN), 256, 0, stream>>>(
        seg2, F_HID, h1, F_HID, Wl2, Wr2, bl2, h2, nullptr, N_TGT2, F_HID, 1);

    // embedding = h2 @ W1^T + b1 (pre-act -> out_emb), h3 = relu(embedding)
    gemm_fused<<<dim3((N_TGT2 + BM - 1) / BM, F_HID / BN), 256, 0, stream>>>(
        h2, F_HID, nullptr, 0, W1, nullptr, b1, h3, out_emb, N_TGT2, F_HID, 1);

    // logits = h3 @ W2^T + b2
    gemm_fused<<<dim3((N_TGT2 + BM - 1) / BM, F_OUT / BN), 256, 0, stream>>>(
        h3, F_HID, nullptr, 0, W2, nullptr, b2, logits, nullptr, N_TGT2, F_OUT, 0);

    // log_softmax rows of 128
    logsoftmax128<<<(N_TGT2 * 64 + 255) / 256, 256, 0, stream>>>(logits, out_ls, N_TGT2);
}

// Round 3
// 479.458 us; speedup vs baseline: 2.6981x; 1.3155x over previous
//
#include <hip/hip_runtime.h>
#include <hip/hip_bf16.h>

// Problem constants
#define N_SRC1 200000
#define N_TGT1 50000
#define N_TGT2 10000
#define E1_N   1000000
#define E2_N   300000
#define F_IN   256
#define F_HID  192
#define F_OUT  128

typedef __attribute__((ext_vector_type(4))) float f32x4;
typedef __attribute__((ext_vector_type(8))) short short8;

__device__ inline float bf2f(ushort u) {
    union { uint i; float f; } c; c.i = ((uint)u) << 16; return c.f;
}
__device__ inline ushort f2bf(float f) {
    union { float f; uint i; } c; c.f = f;
    uint u = c.i;
    return (ushort)((u + 0x7FFFu + ((u >> 16) & 1u)) >> 16);  // RNE
}
__device__ inline uint pack2(float a, float b) {
    return (uint)f2bf(a) | ((uint)f2bf(b) << 16);
}

// ---------------------------------------------------------------------------
// f32 -> bf16 streaming convert (4 elems/thread)
// ---------------------------------------------------------------------------
__global__ __launch_bounds__(256) void f32_to_bf16_vec(
    const float4* __restrict__ src, uint2* __restrict__ dst, int n4)
{
    for (int i = blockIdx.x * blockDim.x + threadIdx.x; i < n4;
         i += gridDim.x * blockDim.x) {
        float4 v = src[i];
        uint2 o;
        o.x = pack2(v.x, v.y);
        o.y = pack2(v.z, v.w);
        dst[i] = o;
    }
}

// Pack [Wa | Wb] (row-major, widths Ka,Kb) into bf16 [N][Ka+Kb]
__global__ __launch_bounds__(256) void pack_w(
    const float* __restrict__ Wa, const float* __restrict__ Wb,
    ushort* __restrict__ dst, int N, int Ka, int Kb)
{
    int K = Ka + Kb, tot = N * K;
    for (int i = blockIdx.x * blockDim.x + threadIdx.x; i < tot;
         i += gridDim.x * blockDim.x) {
        int n = i / K, k = i - n * K;
        float v = (k < Ka) ? Wa[n * Ka + k] : Wb[n * Kb + (k - Ka)];
        dst[i] = f2bf(v);
    }
}

// ---------------------------------------------------------------------------
// CSR build: histogram -> 3-phase exclusive scan -> edge fill
// ---------------------------------------------------------------------------
__global__ __launch_bounds__(256) void hist_kernel(
    const int* __restrict__ tgt, int* __restrict__ cnt, int E)
{
    int i = blockIdx.x * blockDim.x + threadIdx.x;
    if (i < E) atomicAdd(cnt + tgt[i], 1);
}

__global__ __launch_bounds__(256) void scan_blocks(
    const int* __restrict__ cnt, int n, int* __restrict__ off,
    int* __restrict__ partials)
{
    __shared__ int s[256];
    int tid = threadIdx.x;
    int i = blockIdx.x * 256 + tid;
    int v = (i < n) ? cnt[i] : 0;
    s[tid] = v;
    __syncthreads();
#pragma unroll
    for (int o = 1; o < 256; o <<= 1) {
        int t = (tid >= o) ? s[tid - o] : 0;
        __syncthreads();
        s[tid] += t;
        __syncthreads();
    }
    if (i < n) off[i] = s[tid] - v;
    if (tid == 255) partials[blockIdx.x] = s[255];
}

__global__ void scan_partials_serial(int* partials, int np, int* total_out)
{
    int run = 0;
    for (int i = 0; i < np; ++i) { int t = partials[i]; partials[i] = run; run += t; }
    *total_out = run;
}

__global__ __launch_bounds__(256) void add_off(
    int* __restrict__ off, const int* __restrict__ partials,
    int* __restrict__ cur, int n)
{
    int i = blockIdx.x * blockDim.x + threadIdx.x;
    if (i < n) {
        int v = off[i] + partials[i >> 8];
        off[i] = v;
        cur[i] = v;
    }
}

__global__ __launch_bounds__(256) void fill_edges(
    const int* __restrict__ src, const int* __restrict__ tgt,
    int* __restrict__ cur, int* __restrict__ esrc, int E)
{
    int i = blockIdx.x * blockDim.x + threadIdx.x;
    if (i < E) {
        int pos = atomicAdd(cur + tgt[i], 1);
        esrc[pos] = src[i];
    }
}

// ---------------------------------------------------------------------------
// bf16 CSR aggregation (mean folded into store), wave per node.
// ---------------------------------------------------------------------------
__global__ __launch_bounds__(256) void aggregate_bf16_256(
    const int* __restrict__ esrc, const int* __restrict__ off,
    const ushort* __restrict__ X, ushort* __restrict__ seg, int n)
{
    int wid  = blockIdx.x * 4 + (threadIdx.x >> 6);
    int lane = threadIdx.x & 63;
    if (wid >= n) return;
    int s0 = off[wid], s1 = off[wid + 1];
    float a0 = 0, a1 = 0, a2 = 0, a3 = 0;
    const uint2* base = (const uint2*)X;
    for (int e = s0; e < s1; ++e) {
        int s = esrc[e];
        uint2 v = base[(size_t)s * 64 + lane];
        a0 += bf2f((ushort)(v.x & 0xffff)); a1 += bf2f((ushort)(v.x >> 16));
        a2 += bf2f((ushort)(v.y & 0xffff)); a3 += bf2f((ushort)(v.y >> 16));
    }
    float inv = (s1 > s0) ? 1.0f / (float)(s1 - s0) : 0.0f;
    uint2 o;
    o.x = pack2(a0 * inv, a1 * inv);
    o.y = pack2(a2 * inv, a3 * inv);
    ((uint2*)seg)[(size_t)wid * 64 + lane] = o;
}

__global__ __launch_bounds__(256) void aggregate_bf16_192(
    const int* __restrict__ esrc, const int* __restrict__ off,
    const ushort* __restrict__ X, ushort* __restrict__ seg, int n)
{
    int wid  = blockIdx.x * 4 + (threadIdx.x >> 6);
    int lane = threadIdx.x & 63;
    if (wid >= n) return;
    int s0 = off[wid], s1 = off[wid + 1];
    float a0 = 0, a1 = 0, a2 = 0, a3 = 0;
    const uint* base = (const uint*)X;
    for (int e = s0; e < s1; ++e) {
        const uint* r = base + (size_t)esrc[e] * 96;
        uint v0 = r[lane];
        a0 += bf2f((ushort)(v0 & 0xffff)); a1 += bf2f((ushort)(v0 >> 16));
        if (lane < 32) {
            uint v1 = r[64 + lane];
            a2 += bf2f((ushort)(v1 & 0xffff)); a3 += bf2f((ushort)(v1 >> 16));
        }
    }
    float inv = (s1 > s0) ? 1.0f / (float)(s1 - s0) : 0.0f;
    uint* o = (uint*)seg + (size_t)wid * 96;
    o[lane] = pack2(a0 * inv, a1 * inv);
    if (lane < 32) o[64 + lane] = pack2(a2 * inv, a3 * inv);
}

// ---------------------------------------------------------------------------
// MFMA bf16 GEMM. One block covers the FULL N (=BN). A = [A1 | A2] virtual
// K-concat. W = [N][K] bf16. Cb: bf16 out (relu optional); Cf: f32 pre-act.
// 4 waves as 2x2; wave computes (BM/2) x (BN/2) via 16x16x32 MFMA.
// LDS rows padded to 40 ushort (80B stride): 2-way bank conflicts only.
// ---------------------------------------------------------------------------
template <int BM, int BN>
__global__ __launch_bounds__(256) void gemm_mfma(
    const ushort* __restrict__ A1, int K1,
    const ushort* __restrict__ A2, int K2,
    const ushort* __restrict__ W, const float* __restrict__ bias,
    ushort* __restrict__ Cb, float* __restrict__ Cf,
    int M, int relu)
{
    constexpr int MF = BM / 32, NF = BN / 32, ROW = 40;
    __shared__ __attribute__((aligned(16))) ushort As[BM * ROW];
    __shared__ __attribute__((aligned(16))) ushort Ws[BN * ROW];
    const int tid  = threadIdx.x;
    const int lane = tid & 63;
    const int wid  = tid >> 6;
    const int wm = wid >> 1, wn = wid & 1;
    const int bm = blockIdx.x * BM;
    const int K = K1 + K2;

    f32x4 acc[MF][NF];
#pragma unroll
    for (int i = 0; i < MF; ++i)
#pragma unroll
        for (int j = 0; j < NF; ++j) acc[i][j] = {0.f, 0.f, 0.f, 0.f};

    for (int k0 = 0; k0 < K; k0 += 32) {
#pragma unroll
        for (int it = 0; it < BM / 64; ++it) {
            int c = tid + it * 256;
            int row = c >> 2, k8 = (c & 3) * 8;
            int m = bm + row, k = k0 + k8;
            uint4 v = make_uint4(0, 0, 0, 0);
            if (m < M) {
                const ushort* s = (k < K1) ? (A1 + (size_t)m * K1 + k)
                                           : (A2 + (size_t)m * K2 + (k - K1));
                v = *(const uint4*)s;
            }
            *(uint4*)&As[row * ROW + k8] = v;
        }
#pragma unroll
        for (int it = 0; it < BN / 64; ++it) {
            int c = tid + it * 256;
            int row = c >> 2, k8 = (c & 3) * 8;
            uint4 v = *(const uint4*)(W + (size_t)row * K + k0 + k8);
            *(uint4*)&Ws[row * ROW + k8] = v;
        }
        __syncthreads();
        short8 a[MF], b[NF];
#pragma unroll
        for (int mf = 0; mf < MF; ++mf)
            a[mf] = *(const short8*)&As[(wm * (BM / 2) + mf * 16 + (lane & 15)) * ROW + (lane >> 4) * 8];
#pragma unroll
        for (int nf = 0; nf < NF; ++nf)
            b[nf] = *(const short8*)&Ws[(wn * (BN / 2) + nf * 16 + (lane & 15)) * ROW + (lane >> 4) * 8];
#pragma unroll
        for (int mf = 0; mf < MF; ++mf)
#pragma unroll
            for (int nf = 0; nf < NF; ++nf)
                acc[mf][nf] = __builtin_amdgcn_mfma_f32_16x16x32_bf16(
                    a[mf], b[nf], acc[mf][nf], 0, 0, 0);
        __syncthreads();
    }

#pragma unroll
    for (int mf = 0; mf < MF; ++mf) {
        int r0 = bm + wm * (BM / 2) + mf * 16 + (lane >> 4) * 4;
#pragma unroll
        for (int nf = 0; nf < NF; ++nf) {
            int cc = wn * (BN / 2) + nf * 16 + (lane & 15);
            float bi = bias[cc];
#pragma unroll
            for (int r = 0; r < 4; ++r) {
                int m = r0 + r;
                if (m >= M) continue;
                float v = acc[mf][nf][r] + bi;
                if (Cf) Cf[(size_t)m * BN + cc] = v;
                if (Cb) Cb[(size_t)m * BN + cc] = f2bf(relu ? fmaxf(v, 0.f) : v);
            }
        }
    }
}

// ---------------------------------------------------------------------------
// log_softmax over rows of 128 (f32 in/out): one wave per row.
// ---------------------------------------------------------------------------
__global__ __launch_bounds__(256) void logsoftmax128(
    const float* __restrict__ logits, float* __restrict__ out, int M)
{
    long long gid = (long long)blockIdx.x * blockDim.x + threadIdx.x;
    int row  = (int)(gid >> 6);
    int lane = (int)(gid & 63);
    if (row >= M) return;
    const float* r = logits + (size_t)row * 128;
    float a = r[lane], b = r[lane + 64];
    float mx = fmaxf(a, b);
#pragma unroll
    for (int o = 32; o > 0; o >>= 1) mx = fmaxf(mx, __shfl_xor(mx, o));
    float s = expf(a - mx) + expf(b - mx);
#pragma unroll
    for (int o = 32; o > 0; o >>= 1) s += __shfl_xor(s, o);
    float ls = logf(s) + mx;
    out[(size_t)row * 128 + lane]      = a - ls;
    out[(size_t)row * 128 + lane + 64] = b - ls;
}

// ---------------------------------------------------------------------------
extern "C" void kernel_launch(void* const* d_in, const int* in_sizes, int n_in,
                              void* d_out, int out_size, void* d_ws, size_t ws_size,
                              hipStream_t stream)
{
    const float* x   = (const float*)d_in[0];
    const int*   ei1 = (const int*)d_in[1];
    const int*   ei2 = (const int*)d_in[2];
    const float* Wl1 = (const float*)d_in[3];
    const float* bl1 = (const float*)d_in[4];
    const float* Wr1 = (const float*)d_in[5];
    const float* Wl2 = (const float*)d_in[6];
    const float* bl2 = (const float*)d_in[7];
    const float* Wr2 = (const float*)d_in[8];
    const float* W1  = (const float*)d_in[9];
    const float* b1  = (const float*)d_in[10];
    const float* W2  = (const float*)d_in[11];
    const float* b2  = (const float*)d_in[12];

    char* ws = (char*)d_ws;
    // ---- layout (peak ~152.1 MB) ----
    ushort* xb    = (ushort*)(ws + 0);            // 102,400,000  [200000x256]
    ushort* seg1b = (ushort*)(ws + 102400000);    //  25,600,000  [50000x256]
    ushort* h1b   = (ushort*)(ws + 128000000);    //  19,200,000  [50000x192]
    int*    esrc1 = (int*)   (ws + 147200000);    //   4,000,000
    int*    cnt1  = (int*)   (ws + 151200000);    //     200,000
    int*    off1  = (int*)   (ws + 151400000);    //     200,004
    int*    part  = (int*)   (ws + 151600064);    //       1,024
    ushort* wc1   = (ushort*)(ws + 151601152);    //     196,608  [192][512]
    ushort* wc2   = (ushort*)(ws + 151797760);    //     147,456  [192][384]
    ushort* w1b   = (ushort*)(ws + 151945216);    //      73,728  [192][192]
    ushort* w2b   = (ushort*)(ws + 152018944);    //      49,152  [128][192]
    ushort* seg2b = (ushort*)(ws + 152068096);    //   3,840,000  [10000x192]
    // layer-2 CSR overlays dead esrc1 region after agg1:
    int*    esrc2 = (int*)   (ws + 147200000);    //   1,200,000
    int*    cnt2  = (int*)   (ws + 148400000);    //      40,000
    int*    off2  = (int*)   (ws + 148440064);    //      40,004
    // after gemm1 consumes seg1b, reuse its region:
    ushort* h2b    = (ushort*)(ws + 102400000);   //   3,840,000  [10000x192]
    ushort* h3b    = (ushort*)(ws + 106240000);   //   3,840,000
    float*  logits = (float*) (ws + 110080000);   //   5,120,000  [10000x128]

    float* out_ls  = (float*)d_out;                           // [10000,128]
    float* out_emb = (float*)d_out + (size_t)N_TGT2 * F_OUT;  // [10000,192]

    const int NP1 = (N_TGT1 + 255) / 256;  // 196
    const int NP2 = (N_TGT2 + 255) / 256;  // 40

    // ---- conversions ----
    f32_to_bf16_vec<<<2048, 256, 0, stream>>>(
        (const float4*)x, (uint2*)xb, N_SRC1 * F_IN / 4);
    pack_w<<<384, 256, 0, stream>>>(Wl1, Wr1, wc1, F_HID, F_IN, F_IN);
    pack_w<<<288, 256, 0, stream>>>(Wl2, Wr2, wc2, F_HID, F_HID, F_HID);
    pack_w<<<144, 256, 0, stream>>>(W1, nullptr, w1b, F_HID, F_HID, 0);
    pack_w<<<96, 256, 0, stream>>>(W2, nullptr, w2b, F_OUT, F_HID, 0);

    // ---- layer 1: CSR + aggregate (bf16) ----
    hipMemsetAsync(cnt1, 0, 200000, stream);
    hist_kernel<<<(E1_N + 255) / 256, 256, 0, stream>>>(ei1 + E1_N, cnt1, E1_N);
    scan_blocks<<<NP1, 256, 0, stream>>>(cnt1, N_TGT1, off1, part);
    scan_partials_serial<<<1, 1, 0, stream>>>(part, NP1, off1 + N_TGT1);
    add_off<<<NP1, 256, 0, stream>>>(off1, part, cnt1 /*cursor*/, N_TGT1);
    fill_edges<<<(E1_N + 255) / 256, 256, 0, stream>>>(ei1, ei1 + E1_N, cnt1, esrc1, E1_N);
    aggregate_bf16_256<<<(N_TGT1 + 3) / 4, 256, 0, stream>>>(esrc1, off1, xb, seg1b, N_TGT1);

    // h1 = relu([seg1 | x_tgt] @ wc1^T + bl1)   M=50000 N=192 K=512
    gemm_mfma<128, 192><<<(N_TGT1 + 127) / 128, 256, 0, stream>>>(
        seg1b, F_IN, xb, F_IN, wc1, bl1, h1b, nullptr, N_TGT1, 1);

    // ---- layer 2: CSR + aggregate (bf16) ----
    hipMemsetAsync(cnt2, 0, 40000, stream);
    hist_kernel<<<(E2_N + 255) / 256, 256, 0, stream>>>(ei2 + E2_N, cnt2, E2_N);
    scan_blocks<<<NP2, 256, 0, stream>>>(cnt2, N_TGT2, off2, part);
    scan_partials_serial<<<1, 1, 0, stream>>>(part, NP2, off2 + N_TGT2);
    add_off<<<NP2, 256, 0, stream>>>(off2, part, cnt2 /*cursor*/, N_TGT2);
    fill_edges<<<(E2_N + 255) / 256, 256, 0, stream>>>(ei2, ei2 + E2_N, cnt2, esrc2, E2_N);
    aggregate_bf16_192<<<(N_TGT2 + 3) / 4, 256, 0, stream>>>(esrc2, off2, h1b, seg2b, N_TGT2);

    // h2 = relu([seg2 | h1_tgt] @ wc2^T + bl2)  M=10000 N=192 K=384
    gemm_mfma<64, 192><<<(N_TGT2 + 63) / 64, 256, 0, stream>>>(
        seg2b, F_HID, h1b, F_HID, wc2, bl2, h2b, nullptr, N_TGT2, 1);

    // embedding = h2 @ W1^T + b1 (f32 -> out_emb), h3 = relu (bf16)
    gemm_mfma<64, 192><<<(N_TGT2 + 63) / 64, 256, 0, stream>>>(
        h2b, F_HID, nullptr, 0, w1b, b1, h3b, out_emb, N_TGT2, 1);

    // logits = h3 @ W2^T + b2 (f32)
    gemm_mfma<64, 128><<<(N_TGT2 + 63) / 64, 256, 0, stream>>>(
        h3b, F_HID, nullptr, 0, w2b, b2, nullptr, logits, N_TGT2, 0);

    logsoftmax128<<<(N_TGT2 * 64 + 255) / 256, 256, 0, stream>>>(logits, out_ls, N_TGT2);
}

// Round 4
// 396.540 us; speedup vs baseline: 3.2623x; 1.2091x over previous
//
#include <hip/hip_runtime.h>
#include <hip/hip_bf16.h>

// Problem constants
#define N_SRC1 200000
#define N_TGT1 50000
#define N_TGT2 10000
#define E1_N   1000000
#define E2_N   300000
#define F_IN   256
#define F_HID  192
#define F_OUT  128

typedef __attribute__((ext_vector_type(4))) float f32x4;
typedef __attribute__((ext_vector_type(8))) short short8;

__device__ inline float bf2f(ushort u) {
    union { uint i; float f; } c; c.i = ((uint)u) << 16; return c.f;
}
__device__ inline ushort f2bf(float f) {
    union { float f; uint i; } c; c.f = f;
    uint u = c.i;
    return (ushort)((u + 0x7FFFu + ((u >> 16) & 1u)) >> 16);  // RNE
}
__device__ inline uint pack2(float a, float b) {
    return (uint)f2bf(a) | ((uint)f2bf(b) << 16);
}

// ---------------------------------------------------------------------------
// prep: blocks [0,2048): x f32->bf16; blocks [2048,2176): pack all weights
//   wc1 = [Wl1|Wr1] 192x512, wc2 = [Wl2|Wr2] 192x384, w1b 192x192, w2b 128x192
// ---------------------------------------------------------------------------
__global__ __launch_bounds__(256) void prep(
    const float4* __restrict__ x4, uint2* __restrict__ xb,
    const float* __restrict__ Wl1, const float* __restrict__ Wr1,
    const float* __restrict__ Wl2, const float* __restrict__ Wr2,
    const float* __restrict__ W1, const float* __restrict__ W2,
    ushort* __restrict__ wc1, ushort* __restrict__ wc2,
    ushort* __restrict__ w1b, ushort* __restrict__ w2b)
{
    const int b = blockIdx.x, tid = threadIdx.x;
    if (b < 2048) {
        const int n4 = N_SRC1 * F_IN / 4;
        for (int i = b * 256 + tid; i < n4; i += 2048 * 256) {
            float4 v = x4[i];
            uint2 o;
            o.x = pack2(v.x, v.y);
            o.y = pack2(v.z, v.w);
            xb[i] = o;
        }
        return;
    }
    // weights: total 98304 + 73728 + 36864 + 24576 = 233472 elems
    const int wt = (b - 2048) * 256 + tid;          // 0..32767 stride
    for (int idx = wt; idx < 233472; idx += 128 * 256) {
        if (idx < 98304) {                           // wc1: 192 x 512
            int n = idx >> 9, k = idx & 511;
            float v = (k < 256) ? Wl1[n * 256 + k] : Wr1[n * 256 + (k - 256)];
            wc1[idx] = f2bf(v);
        } else if (idx < 98304 + 73728) {            // wc2: 192 x 384
            int i2 = idx - 98304;
            int n = i2 / 384, k = i2 - n * 384;
            float v = (k < 192) ? Wl2[n * 192 + k] : Wr2[n * 192 + (k - 192)];
            wc2[i2] = f2bf(v);
        } else if (idx < 98304 + 73728 + 36864) {    // w1b: 192 x 192
            int i3 = idx - (98304 + 73728);
            w1b[i3] = f2bf(W1[i3]);
        } else {                                     // w2b: 128 x 192
            int i4 = idx - (98304 + 73728 + 36864);
            w2b[i4] = f2bf(W2[i4]);
        }
    }
}

// ---------------------------------------------------------------------------
// CSR build: histogram -> block scan -> parallel partials scan -> add -> fill
// ---------------------------------------------------------------------------
__global__ __launch_bounds__(256) void hist_kernel(
    const int* __restrict__ tgt, int* __restrict__ cnt, int E)
{
    int i = blockIdx.x * blockDim.x + threadIdx.x;
    if (i < E) atomicAdd(cnt + tgt[i], 1);
}

__global__ __launch_bounds__(256) void scan_blocks(
    const int* __restrict__ cnt, int n, int* __restrict__ off,
    int* __restrict__ partials)
{
    __shared__ int s[256];
    int tid = threadIdx.x;
    int i = blockIdx.x * 256 + tid;
    int v = (i < n) ? cnt[i] : 0;
    s[tid] = v;
    __syncthreads();
#pragma unroll
    for (int o = 1; o < 256; o <<= 1) {
        int t = (tid >= o) ? s[tid - o] : 0;
        __syncthreads();
        s[tid] += t;
        __syncthreads();
    }
    if (i < n) off[i] = s[tid] - v;
    if (tid == 255) partials[blockIdx.x] = s[255];
}

// single-block parallel exclusive scan of partials (np <= 256)
__global__ __launch_bounds__(256) void scan_partials_block(
    int* __restrict__ partials, int np, int* __restrict__ total_out)
{
    __shared__ int s[256];
    int tid = threadIdx.x;
    int v = (tid < np) ? partials[tid] : 0;
    s[tid] = v;
    __syncthreads();
#pragma unroll
    for (int o = 1; o < 256; o <<= 1) {
        int t = (tid >= o) ? s[tid - o] : 0;
        __syncthreads();
        s[tid] += t;
        __syncthreads();
    }
    if (tid < np) partials[tid] = s[tid] - v;
    if (tid == 255) *total_out = s[255];
}

__global__ __launch_bounds__(256) void add_off(
    int* __restrict__ off, const int* __restrict__ partials,
    int* __restrict__ cur, int n)
{
    int i = blockIdx.x * blockDim.x + threadIdx.x;
    if (i < n) {
        int v = off[i] + partials[i >> 8];
        off[i] = v;
        cur[i] = v;
    }
}

__global__ __launch_bounds__(256) void fill_edges(
    const int* __restrict__ src, const int* __restrict__ tgt,
    int* __restrict__ cur, int* __restrict__ esrc, int E)
{
    int i = blockIdx.x * blockDim.x + threadIdx.x;
    if (i < E) {
        int pos = atomicAdd(cur + tgt[i], 1);
        esrc[pos] = src[i];
    }
}

// ---------------------------------------------------------------------------
// bf16 CSR aggregation, wave per node, ILP-4 edge unroll.
// ---------------------------------------------------------------------------
__global__ __launch_bounds__(256) void aggregate_bf16_256(
    const int* __restrict__ esrc, const int* __restrict__ off,
    const ushort* __restrict__ X, ushort* __restrict__ seg, int n)
{
    int wid  = blockIdx.x * 4 + (threadIdx.x >> 6);
    int lane = threadIdx.x & 63;
    if (wid >= n) return;
    int s0 = off[wid], s1 = off[wid + 1];
    float a0 = 0, a1 = 0, a2 = 0, a3 = 0;
    const uint2* base = (const uint2*)X;
    int e = s0;
    for (; e + 4 <= s1; e += 4) {
        int i0 = esrc[e], i1 = esrc[e + 1], i2 = esrc[e + 2], i3 = esrc[e + 3];
        uint2 v0 = base[(size_t)i0 * 64 + lane];
        uint2 v1 = base[(size_t)i1 * 64 + lane];
        uint2 v2 = base[(size_t)i2 * 64 + lane];
        uint2 v3 = base[(size_t)i3 * 64 + lane];
        a0 += bf2f((ushort)(v0.x & 0xffff)) + bf2f((ushort)(v1.x & 0xffff))
            + bf2f((ushort)(v2.x & 0xffff)) + bf2f((ushort)(v3.x & 0xffff));
        a1 += bf2f((ushort)(v0.x >> 16)) + bf2f((ushort)(v1.x >> 16))
            + bf2f((ushort)(v2.x >> 16)) + bf2f((ushort)(v3.x >> 16));
        a2 += bf2f((ushort)(v0.y & 0xffff)) + bf2f((ushort)(v1.y & 0xffff))
            + bf2f((ushort)(v2.y & 0xffff)) + bf2f((ushort)(v3.y & 0xffff));
        a3 += bf2f((ushort)(v0.y >> 16)) + bf2f((ushort)(v1.y >> 16))
            + bf2f((ushort)(v2.y >> 16)) + bf2f((ushort)(v3.y >> 16));
    }
    for (; e < s1; ++e) {
        uint2 v = base[(size_t)esrc[e] * 64 + lane];
        a0 += bf2f((ushort)(v.x & 0xffff)); a1 += bf2f((ushort)(v.x >> 16));
        a2 += bf2f((ushort)(v.y & 0xffff)); a3 += bf2f((ushort)(v.y >> 16));
    }
    float inv = (s1 > s0) ? 1.0f / (float)(s1 - s0) : 0.0f;
    uint2 o;
    o.x = pack2(a0 * inv, a1 * inv);
    o.y = pack2(a2 * inv, a3 * inv);
    ((uint2*)seg)[(size_t)wid * 64 + lane] = o;
}

__global__ __launch_bounds__(256) void aggregate_bf16_192(
    const int* __restrict__ esrc, const int* __restrict__ off,
    const ushort* __restrict__ X, ushort* __restrict__ seg, int n)
{
    int wid  = blockIdx.x * 4 + (threadIdx.x >> 6);
    int lane = threadIdx.x & 63;
    if (wid >= n) return;
    int s0 = off[wid], s1 = off[wid + 1];
    float a0 = 0, a1 = 0, a2 = 0, a3 = 0;
    const uint* base = (const uint*)X;
    int e = s0;
    for (; e + 4 <= s1; e += 4) {
        const uint* r0 = base + (size_t)esrc[e] * 96;
        const uint* r1 = base + (size_t)esrc[e + 1] * 96;
        const uint* r2 = base + (size_t)esrc[e + 2] * 96;
        const uint* r3 = base + (size_t)esrc[e + 3] * 96;
        uint w0 = r0[lane], w1 = r1[lane], w2 = r2[lane], w3 = r3[lane];
        a0 += bf2f((ushort)(w0 & 0xffff)) + bf2f((ushort)(w1 & 0xffff))
            + bf2f((ushort)(w2 & 0xffff)) + bf2f((ushort)(w3 & 0xffff));
        a1 += bf2f((ushort)(w0 >> 16)) + bf2f((ushort)(w1 >> 16))
            + bf2f((ushort)(w2 >> 16)) + bf2f((ushort)(w3 >> 16));
        if (lane < 32) {
            uint u0 = r0[64 + lane], u1 = r1[64 + lane],
                 u2 = r2[64 + lane], u3 = r3[64 + lane];
            a2 += bf2f((ushort)(u0 & 0xffff)) + bf2f((ushort)(u1 & 0xffff))
                + bf2f((ushort)(u2 & 0xffff)) + bf2f((ushort)(u3 & 0xffff));
            a3 += bf2f((ushort)(u0 >> 16)) + bf2f((ushort)(u1 >> 16))
                + bf2f((ushort)(u2 >> 16)) + bf2f((ushort)(u3 >> 16));
        }
    }
    for (; e < s1; ++e) {
        const uint* r = base + (size_t)esrc[e] * 96;
        uint v0 = r[lane];
        a0 += bf2f((ushort)(v0 & 0xffff)); a1 += bf2f((ushort)(v0 >> 16));
        if (lane < 32) {
            uint v1 = r[64 + lane];
            a2 += bf2f((ushort)(v1 & 0xffff)); a3 += bf2f((ushort)(v1 >> 16));
        }
    }
    float inv = (s1 > s0) ? 1.0f / (float)(s1 - s0) : 0.0f;
    uint* o = (uint*)seg + (size_t)wid * 96;
    o[lane] = pack2(a0 * inv, a1 * inv);
    if (lane < 32) o[64 + lane] = pack2(a2 * inv, a3 * inv);
}

// ---------------------------------------------------------------------------
// MFMA bf16 GEMM, WM x WN waves (64*WM*WN threads). One block covers full N.
// A = [A1 | A2] virtual K-concat. W = [N][K] bf16.
// Cb: bf16 out (relu optional); Cf: f32 pre-act out.
// LDS rows padded to 40 ushort (80B stride): 2-way bank conflicts only (free).
// ---------------------------------------------------------------------------
template <int BM, int BN, int WM, int WN>
__global__ __launch_bounds__(WM * WN * 64) void gemm_mfma(
    const ushort* __restrict__ A1, int K1,
    const ushort* __restrict__ A2, int K2,
    const ushort* __restrict__ W, const float* __restrict__ bias,
    ushort* __restrict__ Cb, float* __restrict__ Cf,
    int M, int relu)
{
    constexpr int TPB = WM * WN * 64;
    constexpr int WTM = BM / WM, WTN = BN / WN;
    constexpr int MF = WTM / 16, NF = WTN / 16;
    constexpr int ROW = 40;
    __shared__ __attribute__((aligned(16))) ushort As[BM * ROW];
    __shared__ __attribute__((aligned(16))) ushort Ws[BN * ROW];
    const int tid  = threadIdx.x;
    const int lane = tid & 63;
    const int wid  = tid >> 6;
    const int wm = wid / WN, wn = wid % WN;
    const int bm = blockIdx.x * BM;
    const int K = K1 + K2;

    f32x4 acc[MF][NF];
#pragma unroll
    for (int i = 0; i < MF; ++i)
#pragma unroll
        for (int j = 0; j < NF; ++j) acc[i][j] = {0.f, 0.f, 0.f, 0.f};

    for (int k0 = 0; k0 < K; k0 += 32) {
#pragma unroll
        for (int c = tid; c < BM * 4; c += TPB) {
            int row = c >> 2, k8 = (c & 3) * 8;
            int m = bm + row, k = k0 + k8;
            uint4 v = make_uint4(0, 0, 0, 0);
            if (m < M) {
                const ushort* s = (k < K1) ? (A1 + (size_t)m * K1 + k)
                                           : (A2 + (size_t)m * K2 + (k - K1));
                v = *(const uint4*)s;
            }
            *(uint4*)&As[row * ROW + k8] = v;
        }
#pragma unroll
        for (int c = tid; c < BN * 4; c += TPB) {
            int row = c >> 2, k8 = (c & 3) * 8;
            uint4 v = *(const uint4*)(W + (size_t)row * K + k0 + k8);
            *(uint4*)&Ws[row * ROW + k8] = v;
        }
        __syncthreads();
        short8 a[MF], b[NF];
#pragma unroll
        for (int mf = 0; mf < MF; ++mf)
            a[mf] = *(const short8*)&As[(wm * WTM + mf * 16 + (lane & 15)) * ROW + (lane >> 4) * 8];
#pragma unroll
        for (int nf = 0; nf < NF; ++nf)
            b[nf] = *(const short8*)&Ws[(wn * WTN + nf * 16 + (lane & 15)) * ROW + (lane >> 4) * 8];
#pragma unroll
        for (int mf = 0; mf < MF; ++mf)
#pragma unroll
            for (int nf = 0; nf < NF; ++nf)
                acc[mf][nf] = __builtin_amdgcn_mfma_f32_16x16x32_bf16(
                    a[mf], b[nf], acc[mf][nf], 0, 0, 0);
        __syncthreads();
    }

#pragma unroll
    for (int mf = 0; mf < MF; ++mf) {
        int r0 = bm + wm * WTM + mf * 16 + (lane >> 4) * 4;
#pragma unroll
        for (int nf = 0; nf < NF; ++nf) {
            int cc = wn * WTN + nf * 16 + (lane & 15);
            float bi = bias[cc];
#pragma unroll
            for (int r = 0; r < 4; ++r) {
                int m = r0 + r;
                if (m >= M) continue;
                float v = acc[mf][nf][r] + bi;
                if (Cf) Cf[(size_t)m * BN + cc] = v;
                if (Cb) Cb[(size_t)m * BN + cc] = f2bf(relu ? fmaxf(v, 0.f) : v);
            }
        }
    }
}

// ---------------------------------------------------------------------------
// log_softmax over rows of 128 (f32 in/out): one wave per row.
// ---------------------------------------------------------------------------
__global__ __launch_bounds__(256) void logsoftmax128(
    const float* __restrict__ logits, float* __restrict__ out, int M)
{
    long long gid = (long long)blockIdx.x * blockDim.x + threadIdx.x;
    int row  = (int)(gid >> 6);
    int lane = (int)(gid & 63);
    if (row >= M) return;
    const float* r = logits + (size_t)row * 128;
    float a = r[lane], b = r[lane + 64];
    float mx = fmaxf(a, b);
#pragma unroll
    for (int o = 32; o > 0; o >>= 1) mx = fmaxf(mx, __shfl_xor(mx, o));
    float s = expf(a - mx) + expf(b - mx);
#pragma unroll
    for (int o = 32; o > 0; o >>= 1) s += __shfl_xor(s, o);
    float ls = logf(s) + mx;
    out[(size_t)row * 128 + lane]      = a - ls;
    out[(size_t)row * 128 + lane + 64] = b - ls;
}

// ---------------------------------------------------------------------------
extern "C" void kernel_launch(void* const* d_in, const int* in_sizes, int n_in,
                              void* d_out, int out_size, void* d_ws, size_t ws_size,
                              hipStream_t stream)
{
    const float* x   = (const float*)d_in[0];
    const int*   ei1 = (const int*)d_in[1];
    const int*   ei2 = (const int*)d_in[2];
    const float* Wl1 = (const float*)d_in[3];
    const float* bl1 = (const float*)d_in[4];
    const float* Wr1 = (const float*)d_in[5];
    const float* Wl2 = (const float*)d_in[6];
    const float* bl2 = (const float*)d_in[7];
    const float* Wr2 = (const float*)d_in[8];
    const float* W1  = (const float*)d_in[9];
    const float* b1  = (const float*)d_in[10];
    const float* W2  = (const float*)d_in[11];
    const float* b2  = (const float*)d_in[12];

    char* ws = (char*)d_ws;
    // ---- layout (peak ~156 MB) ----
    ushort* xb    = (ushort*)(ws + 0);            // 102,400,000  [200000x256]
    ushort* seg1b = (ushort*)(ws + 102400000);    //  25,600,000  [50000x256]
    ushort* h1b   = (ushort*)(ws + 128000000);    //  19,200,000  [50000x192]
    int*    esrc1 = (int*)   (ws + 147200000);    //   4,000,000
    int*    cnt1  = (int*)   (ws + 151200000);    //     200,000
    int*    off1  = (int*)   (ws + 151400000);    //     200,004
    int*    part  = (int*)   (ws + 151600064);    //       1,024
    ushort* wc1   = (ushort*)(ws + 151601152);    //     196,608  [192][512]
    ushort* wc2   = (ushort*)(ws + 151797760);    //     147,456  [192][384]
    ushort* w1b   = (ushort*)(ws + 151945216);    //      73,728  [192][192]
    ushort* w2b   = (ushort*)(ws + 152018944);    //      49,152  [128][192]
    ushort* seg2b = (ushort*)(ws + 152068096);    //   3,840,000  [10000x192]
    // layer-2 CSR overlays dead esrc1 region after agg1:
    int*    esrc2 = (int*)   (ws + 147200000);    //   1,200,000
    int*    cnt2  = (int*)   (ws + 148400000);    //      40,000
    int*    off2  = (int*)   (ws + 148440064);    //      40,004
    // after gemm1 consumes seg1b, reuse its region:
    ushort* h2b    = (ushort*)(ws + 102400000);   //   3,840,000  [10000x192]
    ushort* h3b    = (ushort*)(ws + 106240000);   //   3,840,000
    float*  logits = (float*) (ws + 110080000);   //   5,120,000  [10000x128]

    float* out_ls  = (float*)d_out;                           // [10000,128]
    float* out_emb = (float*)d_out + (size_t)N_TGT2 * F_OUT;  // [10000,192]

    const int NP1 = (N_TGT1 + 255) / 256;  // 196
    const int NP2 = (N_TGT2 + 255) / 256;  // 40

    // ---- conversions (single launch) ----
    prep<<<2176, 256, 0, stream>>>(
        (const float4*)x, (uint2*)xb, Wl1, Wr1, Wl2, Wr2, W1, W2,
        wc1, wc2, w1b, w2b);

    // ---- layer 1: CSR + aggregate (bf16) ----
    hipMemsetAsync(cnt1, 0, 200000, stream);
    hist_kernel<<<(E1_N + 255) / 256, 256, 0, stream>>>(ei1 + E1_N, cnt1, E1_N);
    scan_blocks<<<NP1, 256, 0, stream>>>(cnt1, N_TGT1, off1, part);
    scan_partials_block<<<1, 256, 0, stream>>>(part, NP1, off1 + N_TGT1);
    add_off<<<NP1, 256, 0, stream>>>(off1, part, cnt1 /*cursor*/, N_TGT1);
    fill_edges<<<(E1_N + 255) / 256, 256, 0, stream>>>(ei1, ei1 + E1_N, cnt1, esrc1, E1_N);
    aggregate_bf16_256<<<(N_TGT1 + 3) / 4, 256, 0, stream>>>(esrc1, off1, xb, seg1b, N_TGT1);

    // h1 = relu([seg1 | x_tgt] @ wc1^T + bl1)   M=50000 N=192 K=512
    gemm_mfma<128, 192, 4, 2><<<(N_TGT1 + 127) / 128, 512, 0, stream>>>(
        seg1b, F_IN, xb, F_IN, wc1, bl1, h1b, nullptr, N_TGT1, 1);

    // ---- layer 2: CSR + aggregate (bf16) ----
    hipMemsetAsync(cnt2, 0, 40000, stream);
    hist_kernel<<<(E2_N + 255) / 256, 256, 0, stream>>>(ei2 + E2_N, cnt2, E2_N);
    scan_blocks<<<NP2, 256, 0, stream>>>(cnt2, N_TGT2, off2, part);
    scan_partials_block<<<1, 256, 0, stream>>>(part, NP2, off2 + N_TGT2);
    add_off<<<NP2, 256, 0, stream>>>(off2, part, cnt2 /*cursor*/, N_TGT2);
    fill_edges<<<(E2_N + 255) / 256, 256, 0, stream>>>(ei2, ei2 + E2_N, cnt2, esrc2, E2_N);
    aggregate_bf16_192<<<(N_TGT2 + 3) / 4, 256, 0, stream>>>(esrc2, off2, h1b, seg2b, N_TGT2);

    // h2 = relu([seg2 | h1_tgt] @ wc2^T + bl2)  M=10000 N=192 K=384
    gemm_mfma<64, 192, 4, 2><<<(N_TGT2 + 63) / 64, 512, 0, stream>>>(
        seg2b, F_HID, h1b, F_HID, wc2, bl2, h2b, nullptr, N_TGT2, 1);

    // embedding = h2 @ W1^T + b1 (f32 -> out_emb), h3 = relu (bf16)
    gemm_mfma<64, 192, 4, 2><<<(N_TGT2 + 63) / 64, 512, 0, stream>>>(
        h2b, F_HID, nullptr, 0, w1b, b1, h3b, out_emb, N_TGT2, 1);

    // logits = h3 @ W2^T + b2 (f32)
    gemm_mfma<64, 128, 4, 2><<<(N_TGT2 + 63) / 64, 512, 0, stream>>>(
        h3b, F_HID, nullptr, 0, w2b, b2, nullptr, logits, N_TGT2, 0);

    logsoftmax128<<<(N_TGT2 * 64 + 255) / 256, 256, 0, stream>>>(logits, out_ls, N_TGT2);
}